// Round 4
// baseline (1071.324 us; speedup 1.0000x reference)
//
#include <hip/hip_runtime.h>
#include <stdint.h>

typedef unsigned short u16;
typedef __attribute__((ext_vector_type(4))) float f32x4;
typedef __attribute__((ext_vector_type(8))) __bf16 bf16x8;

__device__ __forceinline__ float b2f(u16 u) {
  union { unsigned int i; float f; } v; v.i = ((unsigned int)u) << 16; return v.f;
}
__device__ __forceinline__ u16 f2b(float f) {
  union { float f; unsigned int i; } v; v.f = f;
  unsigned int x = v.i;
  return (u16)((x + 0x7fffu + ((x >> 16) & 1u)) >> 16);
}

// ---- dtype detection: flag=1 if inputs are f32, 0 if bf16 ------------------
// f32 N(0,1) data: low halfwords are uniform mantissa bits -> exponent 0xFF
// appears w.p. ~1/256 per halfword. bf16 N(0,1) data: never.
__global__ void detect_kernel(const u16* __restrict__ x, int* __restrict__ flag)
{
  const int tid = threadIdx.x;
  int found = 0;
  for (int i = tid; i < 32768; i += 256) {
    u16 u = x[i];
    if ((u & 0x7F80u) == 0x7F80u) found = 1;
  }
  unsigned long long m = __ballot(found != 0);
  __shared__ int sf[4];
  if ((tid & 63) == 0) sf[tid >> 6] = (m != 0ULL) ? 1 : 0;
  __syncthreads();
  if (tid == 0) flag[0] = (sf[0] | sf[1] | sf[2] | sf[3]);
}

// normalize an input buffer to bf16 (n multiple of 8)
__global__ __launch_bounds__(256)
void conv_kernel(const void* __restrict__ in, u16* __restrict__ out, long n,
                 const int* __restrict__ flag)
{
  const long i = ((long)blockIdx.x * 256 + threadIdx.x) * 8;
  if (i >= n) return;
  if (flag[0]) {
    const float* p = (const float*)in + i;
    u16 o[8];
#pragma unroll
    for (int j = 0; j < 8; j++) o[j] = f2b(p[j]);
    *(uint4*)(out + i) = *(const uint4*)o;
  } else {
    *(uint4*)(out + i) = *(const uint4*)((const u16*)in + i);
  }
}

#define BM 128
#define BN 128
#define BK 32

// C[m,n] = sum_k A[m,k] * B[n,k]   (A: [M,K] row-major, B: [N,K] row-major)
// EPI 0: C(bf16) = acc + bias[n]
// EPI 1: C(bf16) = acc
// EPI 2: C(bf16) = sigmoid(Q[m,n]) * acc / Den[m,n]
// EPI 3: C(flag? f32 : bf16)[strideC + idx] = acc + bias[n]   (grid.z==1)
template<int EPI>
__global__ __launch_bounds__(256)
void gemm_bt(const u16* __restrict__ A, const u16* __restrict__ B,
             const void* __restrict__ bias, void* __restrict__ Cv,
             const u16* __restrict__ Qp, const u16* __restrict__ Dp,
             const int* __restrict__ flag,
             int M, int N, int K, long strideB, long strideC)
{
  __shared__ __align__(16) u16 sA[BM * BK];
  __shared__ __align__(16) u16 sB[BN * BK];

  const int tid  = threadIdx.x;
  const int lane = tid & 63;
  const int wv   = tid >> 6;
  const int bz   = blockIdx.z;

  int fl = 0;
  if (EPI == 0 || EPI == 3) fl = flag[0];

  const u16* Bb = B + (long)bz * strideB;
  u16* Cb16 = (EPI == 3) ? nullptr : ((u16*)Cv + (long)bz * strideC);
  const u16* Qb = (EPI == 2) ? (Qp + (long)bz * strideC) : nullptr;
  const u16* Db = (EPI == 2) ? (Dp + (long)bz * strideC) : nullptr;

  const int m0 = blockIdx.x * BM;
  const int n0 = blockIdx.y * BN;

  const int srow = tid >> 2;        // 0..63
  const int sch  = (tid & 3) * 8;   // element offset within 32-elem row
  const u16* gA0 = A  + (long)(m0 + srow) * K + sch;
  const u16* gA1 = A  + (long)(m0 + 64 + srow) * K + sch;
  const u16* gB0 = Bb + (long)(n0 + srow) * K + sch;
  const u16* gB1 = Bb + (long)(n0 + 64 + srow) * K + sch;
  u16* lA0 = sA + srow * BK + sch;
  u16* lA1 = sA + (64 + srow) * BK + sch;
  u16* lB0 = sB + srow * BK + sch;
  u16* lB1 = sB + (64 + srow) * BK + sch;

  f32x4 acc[4][4];
#pragma unroll
  for (int i = 0; i < 4; i++)
#pragma unroll
    for (int j = 0; j < 4; j++) acc[i][j] = (f32x4)0.0f;

  const int waveM = (wv >> 1) * 64;
  const int waveN = (wv & 1) * 64;
  const int quad  = lane >> 4;
  const int ll    = lane & 15;

  for (int k0 = 0; k0 < K; k0 += BK) {
    uint4 ra0 = *(const uint4*)gA0;
    uint4 ra1 = *(const uint4*)gA1;
    uint4 rb0 = *(const uint4*)gB0;
    uint4 rb1 = *(const uint4*)gB1;
    gA0 += BK; gA1 += BK; gB0 += BK; gB1 += BK;

    __syncthreads();   // previous tile fully consumed
    *(uint4*)lA0 = ra0;
    *(uint4*)lA1 = ra1;
    *(uint4*)lB0 = rb0;
    *(uint4*)lB1 = rb1;
    __syncthreads();   // current tile published

    bf16x8 aF[4], bF[4];
#pragma unroll
    for (int i = 0; i < 4; i++) {
      aF[i] = *(const bf16x8*)(sA + (waveM + i * 16 + ll) * BK + quad * 8);
      bF[i] = *(const bf16x8*)(sB + (waveN + i * 16 + ll) * BK + quad * 8);
    }
#pragma unroll
    for (int i = 0; i < 4; i++)
#pragma unroll
      for (int j = 0; j < 4; j++)
        acc[i][j] = __builtin_amdgcn_mfma_f32_16x16x32_bf16(aF[i], bF[j], acc[i][j], 0, 0, 0);
  }

  // epilogue: C/D layout col = lane&15, row = quad*4 + r
#pragma unroll
  for (int i = 0; i < 4; i++) {
    const int rowb = m0 + waveM + i * 16 + quad * 4;
#pragma unroll
    for (int j = 0; j < 4; j++) {
      const int col = n0 + waveN + j * 16 + ll;
      float bv = 0.0f;
      if (EPI == 0 || EPI == 3)
        bv = fl ? ((const float*)bias)[col] : b2f(((const u16*)bias)[col]);
#pragma unroll
      for (int r = 0; r < 4; r++) {
        const long idx = (long)(rowb + r) * N + col;
        float v = acc[i][j][r];
        if (EPI == 0) {
          Cb16[idx] = f2b(v + bv);
        } else if (EPI == 1) {
          Cb16[idx] = f2b(v);
        } else if (EPI == 2) {
          float q  = b2f(Qb[idx]);
          float dn = b2f(Db[idx]);
          float sg = 1.0f / (1.0f + __expf(-q));
          Cb16[idx] = f2b(sg * v / dn);
        } else {
          const long g = strideC + idx;
          if (fl) ((float*)Cv)[g] = v + bv;
          else    ((u16*)Cv)[g]   = f2b(v + bv);
        }
      }
    }
  }
}

// exp_w[t,s] = exp(w[t,s] - max_s w[t,s]) ; w read per flag dtype
__global__ __launch_bounds__(256)
void expw_kernel(const void* __restrict__ w, u16* __restrict__ ew,
                 const int* __restrict__ flag)
{
  const int fl = flag[0];
  const int t = blockIdx.x;
  const int tid = threadIdx.x;
  float v[4];
  float m = -1e30f;
#pragma unroll
  for (int i = 0; i < 4; i++) {
    const long idx = (long)t * 1024 + tid + i * 256;
    float val = fl ? ((const float*)w)[idx] : b2f(((const u16*)w)[idx]);
    v[i] = val; m = fmaxf(m, val);
  }
#pragma unroll
  for (int off = 32; off > 0; off >>= 1) m = fmaxf(m, __shfl_xor(m, off, 64));
  __shared__ float sm[4];
  if ((tid & 63) == 0) sm[tid >> 6] = m;
  __syncthreads();
  m = fmaxf(fmaxf(sm[0], sm[1]), fmaxf(sm[2], sm[3]));
  u16* orow = ew + (long)t * 1024;
#pragma unroll
  for (int i = 0; i < 4; i++) orow[tid + i * 256] = f2b(__expf(v[i] - m));
}

// Kmax[t,d] = max_b K[b,t,d]   (over the FULL batch of 32; K is our bf16 buf)
__global__ __launch_bounds__(256)
void kmax_kernel(const u16* __restrict__ K, u16* __restrict__ Km)
{
  const long TD = 1024L * 512;
  const long base = ((long)blockIdx.x * 256 + threadIdx.x) * 8;
  float m[8];
#pragma unroll
  for (int j = 0; j < 8; j++) m[j] = -1e30f;
  for (int b = 0; b < 32; b++) {
    uint4 u = *(const uint4*)(K + b * TD + base);
    const u16* p = (const u16*)&u;
#pragma unroll
    for (int j = 0; j < 8; j++) m[j] = fmaxf(m[j], b2f(p[j]));
  }
  u16 outv[8];
#pragma unroll
  for (int j = 0; j < 8; j++) outv[j] = f2b(m[j]);
  *(uint4*)(Km + base) = *(const uint4*)outv;
}

// P = exp(K - Kmax), PV = P*V ; write transposed: Pt[b,d,s], PVt[b,d,s]
// b here is chunk-local (pointers pre-offset by chunk base).
__global__ __launch_bounds__(256)
void pexp_kernel(const u16* __restrict__ K, const u16* __restrict__ V,
                 const u16* __restrict__ Km,
                 u16* __restrict__ Pt, u16* __restrict__ PVt)
{
  const int T = 1024, D = 512;
  const long TD = (long)T * D;
  const int s0 = blockIdx.x * 64;
  const int d0 = blockIdx.y * 64;
  const int b  = blockIdx.z;
  __shared__ u16 lp[64 * 66];
  __shared__ u16 lpv[64 * 66];
  const int tid  = threadIdx.x;
  const int srow = tid >> 3;           // 0..31
  const int c8   = (tid & 7) * 8;      // 0..56

#pragma unroll
  for (int h = 0; h < 2; h++) {
    const int s = srow + h * 32;
    const long gidx = (long)b * TD + (long)(s0 + s) * D + d0 + c8;
    uint4 ku = *(const uint4*)(K + gidx);
    uint4 vu = *(const uint4*)(V + gidx);
    uint4 mu = *(const uint4*)(Km + (long)(s0 + s) * D + d0 + c8);
    const u16* kp = (const u16*)&ku;
    const u16* vp = (const u16*)&vu;
    const u16* mp = (const u16*)&mu;
#pragma unroll
    for (int j = 0; j < 8; j++) {
      float p  = __expf(b2f(kp[j]) - b2f(mp[j]));
      float pv = p * b2f(vp[j]);
      lp[s * 66 + c8 + j]  = f2b(p);
      lpv[s * 66 + c8 + j] = f2b(pv);
    }
  }
  __syncthreads();

  const int lane = tid & 63;
  const int wv   = tid >> 6;
#pragma unroll
  for (int it = 0; it < 16; it++) {
    const int d = wv * 16 + it;
    const long oidx = (long)b * TD + (long)(d0 + d) * T + s0 + lane;
    Pt[oidx]  = lp[lane * 66 + d];
    PVt[oidx] = lpv[lane * 66 + d];
  }
}

extern "C" void kernel_launch(void* const* d_in, const int* in_sizes, int n_in,
                              void* d_out, int out_size, void* d_ws, size_t ws_size,
                              hipStream_t stream)
{
  const int B = 32, T = 1024, D = 512;
  const long TD = (long)T * D;
  const int NB = 4;               // batches per chunk
  const int NC = B / NB;          // 8 chunks
  const void* x    = d_in[0];
  const void* Wk_w = d_in[1];
  const void* Wk_b = d_in[2];
  const void* Wv_w = d_in[3];
  const void* Wv_b = d_in[4];
  const void* Wq_w = d_in[5];
  const void* Wq_b = d_in[6];
  const void* w    = d_in[7];
  const void* Wo_w = d_in[8];
  const void* Wo_b = d_in[9];

  // Workspace layout (~90 MB)
  char* ws = (char*)d_ws;
  const size_t MB = 1024 * 1024;
  u16* xb   = (u16*)(ws + 0);         // 32MB  [B*T, D] bf16
  u16* Kbuf = (u16*)(ws + 32 * MB);   // 32MB  [B, T, D]
  u16* ewb  = (u16*)(ws + 64 * MB);   // 2MB   [T, T]
  u16* kmb  = (u16*)(ws + 66 * MB);   // 1MB   [T, D]
  u16* Wkb  = (u16*)(ws + 67 * MB);        // 0.5MB each
  u16* Wvb  = (u16*)(ws + 67 * MB + 512 * 1024);
  u16* Wqb  = (u16*)(ws + 68 * MB);
  u16* Wob  = (u16*)(ws + 68 * MB + 512 * 1024);
  u16* Vc   = (u16*)(ws + 69 * MB);   // 4MB   [NB, T, D] (aliased Ytc)
  u16* Ptc  = (u16*)(ws + 73 * MB);   // 4MB   [NB, D, T]
  u16* PVtc = (u16*)(ws + 77 * MB);   // 4MB   [NB, D, T]
  u16* denc = (u16*)(ws + 81 * MB);   // 4MB   [NB, T, D]
  u16* Qc   = (u16*)(ws + 85 * MB);   // 4MB   [NB, T, D]
  int* flag = (int*)(ws + 89 * MB);
  u16* Ytc  = Vc;                     // Vc dead after pexp

  dim3 blk(256);

  // 0) dtype detect + normalize inputs to bf16
  detect_kernel<<<dim3(1), blk, 0, stream>>>((const u16*)x, flag);
  conv_kernel<<<dim3(8192), blk, 0, stream>>>(x,    xb,  (long)B * T * D, flag);
  conv_kernel<<<dim3(128),  blk, 0, stream>>>(Wk_w, Wkb, (long)D * D, flag);
  conv_kernel<<<dim3(128),  blk, 0, stream>>>(Wv_w, Wvb, (long)D * D, flag);
  conv_kernel<<<dim3(128),  blk, 0, stream>>>(Wq_w, Wqb, (long)D * D, flag);
  conv_kernel<<<dim3(128),  blk, 0, stream>>>(Wo_w, Wob, (long)D * D, flag);

  // 1) exp_w
  expw_kernel<<<dim3(1024), blk, 0, stream>>>(w, ewb, flag);

  // 2) K projection for the FULL batch (kmax couples batches)
  dim3 gK((B * T) / 128, D / 128, 1);
  gemm_bt<0><<<gK, blk, 0, stream>>>(xb, Wkb, Wk_b, Kbuf, nullptr, nullptr, flag,
                                     B * T, D, D, 0, 0);

  // 3) Kmax over batch
  kmax_kernel<<<dim3(256), blk, 0, stream>>>(Kbuf, kmb);

  // 4) per-chunk pipeline
  dim3 gP((NB * T) / 128, D / 128, 1);   // chunk projections: M = NB*T
  dim3 gA(T / 128, D / 128, NB);         // aft GEMMs: per-b
  for (int c = 0; c < NC; c++) {
    const long off = (long)c * NB * TD;

    // V, Q projections for this chunk
    gemm_bt<0><<<gP, blk, 0, stream>>>(xb + off, Wvb, Wv_b, Vc, nullptr, nullptr, flag,
                                       NB * T, D, D, 0, 0);
    gemm_bt<0><<<gP, blk, 0, stream>>>(xb + off, Wqb, Wq_b, Qc, nullptr, nullptr, flag,
                                       NB * T, D, D, 0, 0);

    // P/PV + transpose to [b, d, s] for this chunk
    pexp_kernel<<<dim3(16, 8, NB), blk, 0, stream>>>(Kbuf + off, Vc, kmb, Ptc, PVtc);

    // den = expw @ P
    gemm_bt<1><<<gA, blk, 0, stream>>>(ewb, Ptc, nullptr, denc, nullptr, nullptr, flag,
                                       T, D, T, (long)D * T, TD);

    // num = expw @ PV, fused Yt = sigmoid(Q)*num/den  (Ytc overwrites dead Vc)
    gemm_bt<2><<<gA, blk, 0, stream>>>(ewb, PVtc, nullptr, Ytc, Qc, denc, flag,
                                       T, D, T, (long)D * T, TD);

    // out = Yt @ Wo^T + b  (store dtype per flag; strideC = chunk element base)
    gemm_bt<3><<<gP, blk, 0, stream>>>(Ytc, Wob, Wo_b, d_out, nullptr, nullptr, flag,
                                       NB * T, D, D, 0, off);
  }
}

// Round 5
// 937.317 us; speedup vs baseline: 1.1430x; 1.1430x over previous
//
#include <hip/hip_runtime.h>
#include <stdint.h>

typedef unsigned short u16;
typedef __attribute__((ext_vector_type(4))) float f32x4;
typedef __attribute__((ext_vector_type(8))) __bf16 bf16x8;

__device__ __forceinline__ float b2f(u16 u) {
  union { unsigned int i; float f; } v; v.i = ((unsigned int)u) << 16; return v.f;
}
__device__ __forceinline__ u16 f2b(float f) {
  union { float f; unsigned int i; } v; v.f = f;
  unsigned int x = v.i;
  return (u16)((x + 0x7fffu + ((x >> 16) & 1u)) >> 16);
}

// async global->LDS, 16B per lane. HW semantics: LDS dest = firstlane(base) + lane*16,
// which matches our contiguous row layout exactly (verified m97 pattern).
__device__ __forceinline__ void async_ld16(const u16* g, u16* l) {
  __builtin_amdgcn_global_load_lds((const __attribute__((address_space(1))) void*)g,
                                   (__attribute__((address_space(3))) void*)l, 16, 0, 0);
}

// ---- dtype detection: flag=1 if inputs are f32, 0 if bf16 ------------------
__global__ void detect_kernel(const u16* __restrict__ x, int* __restrict__ flag)
{
  const int tid = threadIdx.x;
  int found = 0;
  for (int i = tid; i < 32768; i += 256) {
    u16 u = x[i];
    if ((u & 0x7F80u) == 0x7F80u) found = 1;
  }
  unsigned long long m = __ballot(found != 0);
  __shared__ int sf[4];
  if ((tid & 63) == 0) sf[tid >> 6] = (m != 0ULL) ? 1 : 0;
  __syncthreads();
  if (tid == 0) flag[0] = (sf[0] | sf[1] | sf[2] | sf[3]);
}

// normalize an input buffer to bf16 (n multiple of 8)
__global__ __launch_bounds__(256)
void conv_kernel(const void* __restrict__ in, u16* __restrict__ out, long n,
                 const int* __restrict__ flag)
{
  const long i = ((long)blockIdx.x * 256 + threadIdx.x) * 8;
  if (i >= n) return;
  if (flag[0]) {
    const float* p = (const float*)in + i;
    u16 o[8];
#pragma unroll
    for (int j = 0; j < 8; j++) o[j] = f2b(p[j]);
    *(uint4*)(out + i) = *(const uint4*)o;
  } else {
    *(uint4*)(out + i) = *(const uint4*)((const u16*)in + i);
  }
}

#define BM 128
#define BN 128
#define BK 32

// C[m,n] = sum_k A[m,k] * B[n,k]; async-LDS staged.
// EPI 0: C(bf16) = acc + bias[n]
// EPI 3: C(flag? f32 : bf16)[strideC + idx] = acc + bias[n]   (grid.z==1)
template<int EPI>
__global__ __launch_bounds__(256)
void gemm_bt(const u16* __restrict__ A, const u16* __restrict__ B,
             const void* __restrict__ bias, void* __restrict__ Cv,
             const int* __restrict__ flag,
             int M, int N, int K, long strideC)
{
  __shared__ __align__(16) u16 sA[BM * BK];
  __shared__ __align__(16) u16 sB[BN * BK];

  const int tid  = threadIdx.x;
  const int lane = tid & 63;
  const int wv   = tid >> 6;

  const int fl = flag[0];
  u16* Cb16 = (u16*)Cv;

  const int m0 = blockIdx.x * BM;
  const int n0 = blockIdx.y * BN;

  // wave wv stages rows [wv*32, wv*32+32) of each tile; lane covers
  // row lr=lane>>2, 16B chunk lc=lane&3 -> LDS offset = lane*16 from wave base.
  const int ldRow = wv * 32;
  const int lr = lane >> 2;
  const int lc = lane & 3;
  const u16* gA = A + (long)(m0 + ldRow + lr) * K + lc * 8;
  const u16* gB = B + (long)(n0 + ldRow + lr) * K + lc * 8;
  u16* lA0 = sA + (ldRow + lr) * BK + lc * 8;
  u16* lA1 = sA + (ldRow + 16 + lr) * BK + lc * 8;
  u16* lB0 = sB + (ldRow + lr) * BK + lc * 8;
  u16* lB1 = sB + (ldRow + 16 + lr) * BK + lc * 8;

  f32x4 acc[4][4];
#pragma unroll
  for (int i = 0; i < 4; i++)
#pragma unroll
    for (int j = 0; j < 4; j++) acc[i][j] = (f32x4)0.0f;

  const int waveM = (wv >> 1) * 64;
  const int waveN = (wv & 1) * 64;
  const int quad  = lane >> 4;
  const int ll    = lane & 15;

  for (int k0 = 0; k0 < K; k0 += BK) {
    async_ld16(gA,          lA0);
    async_ld16(gA + 16 * K, lA1);
    async_ld16(gB,          lB0);
    async_ld16(gB + 16 * K, lB1);
    gA += BK; gB += BK;
    __syncthreads();   // drains vmcnt -> tile published

    bf16x8 aF[4], bF[4];
#pragma unroll
    for (int i = 0; i < 4; i++) {
      aF[i] = *(const bf16x8*)(sA + (waveM + i * 16 + ll) * BK + quad * 8);
      bF[i] = *(const bf16x8*)(sB + (waveN + i * 16 + ll) * BK + quad * 8);
    }
#pragma unroll
    for (int i = 0; i < 4; i++)
#pragma unroll
      for (int j = 0; j < 4; j++)
        acc[i][j] = __builtin_amdgcn_mfma_f32_16x16x32_bf16(aF[i], bF[j], acc[i][j], 0, 0, 0);
    __syncthreads();   // all consumed before next issue
  }

  // epilogue: C/D layout col = lane&15, row = quad*4 + r
#pragma unroll
  for (int i = 0; i < 4; i++) {
    const int rowb = m0 + waveM + i * 16 + quad * 4;
#pragma unroll
    for (int j = 0; j < 4; j++) {
      const int col = n0 + waveN + j * 16 + ll;
      const float bv = fl ? ((const float*)bias)[col] : b2f(((const u16*)bias)[col]);
#pragma unroll
      for (int r = 0; r < 4; r++) {
        const long idx = (long)(rowb + r) * N + col;
        const float v = acc[i][j][r] + bv;
        if (EPI == 0) {
          Cb16[idx] = f2b(v);
        } else {
          const long g = strideC + idx;
          if (fl) ((float*)Cv)[g] = v;
          else    ((u16*)Cv)[g]   = f2b(v);
        }
      }
    }
  }
}

// Dual GEMM over shared A=exp_w: num = ew @ PVt^T, den = ew @ Pt^T,
// epilogue Yt = sigmoid(Q) * num / den.  Per-b via blockIdx.z.
// Pt/PVt: [b, D, T] (B-transposed form), Q/Yt: [b, T, D].
__global__ __launch_bounds__(256)
void gemm_aft(const u16* __restrict__ ew, const u16* __restrict__ Pt,
              const u16* __restrict__ PVt, const u16* __restrict__ Q,
              u16* __restrict__ Yt)
{
  const int T = 1024, D = 512;
  __shared__ __align__(16) u16 sA[BM * BK];
  __shared__ __align__(16) u16 sB[BN * BK];  // Pt tile
  __shared__ __align__(16) u16 sC[BN * BK];  // PVt tile

  const int tid  = threadIdx.x;
  const int lane = tid & 63;
  const int wv   = tid >> 6;
  const int b    = blockIdx.z;

  const u16* Ptb  = Pt  + (long)b * D * T;
  const u16* PVtb = PVt + (long)b * D * T;
  const u16* Qb   = Q   + (long)b * T * D;
  u16*       Ytb  = Yt  + (long)b * T * D;

  const int m0 = blockIdx.x * BM;   // t
  const int n0 = blockIdx.y * BN;   // d

  const int ldRow = wv * 32;
  const int lr = lane >> 2;
  const int lc = lane & 3;
  const u16* gA = ew   + (long)(m0 + ldRow + lr) * T + lc * 8;
  const u16* gB = Ptb  + (long)(n0 + ldRow + lr) * T + lc * 8;
  const u16* gC = PVtb + (long)(n0 + ldRow + lr) * T + lc * 8;
  u16* lA0 = sA + (ldRow + lr) * BK + lc * 8;
  u16* lA1 = sA + (ldRow + 16 + lr) * BK + lc * 8;
  u16* lB0 = sB + (ldRow + lr) * BK + lc * 8;
  u16* lB1 = sB + (ldRow + 16 + lr) * BK + lc * 8;
  u16* lC0 = sC + (ldRow + lr) * BK + lc * 8;
  u16* lC1 = sC + (ldRow + 16 + lr) * BK + lc * 8;

  f32x4 accN[4][4], accD[4][4];
#pragma unroll
  for (int i = 0; i < 4; i++)
#pragma unroll
    for (int j = 0; j < 4; j++) { accN[i][j] = (f32x4)0.0f; accD[i][j] = (f32x4)0.0f; }

  const int waveM = (wv >> 1) * 64;
  const int waveN = (wv & 1) * 64;
  const int quad  = lane >> 4;
  const int ll    = lane & 15;

  for (int k0 = 0; k0 < T; k0 += BK) {
    async_ld16(gA,          lA0);
    async_ld16(gA + 16 * T, lA1);
    async_ld16(gB,          lB0);
    async_ld16(gB + 16 * T, lB1);
    async_ld16(gC,          lC0);
    async_ld16(gC + 16 * T, lC1);
    gA += BK; gB += BK; gC += BK;
    __syncthreads();

    bf16x8 aF[4], bF[4], cF[4];
#pragma unroll
    for (int i = 0; i < 4; i++) {
      aF[i] = *(const bf16x8*)(sA + (waveM + i * 16 + ll) * BK + quad * 8);
      bF[i] = *(const bf16x8*)(sB + (waveN + i * 16 + ll) * BK + quad * 8);
      cF[i] = *(const bf16x8*)(sC + (waveN + i * 16 + ll) * BK + quad * 8);
    }
#pragma unroll
    for (int i = 0; i < 4; i++)
#pragma unroll
      for (int j = 0; j < 4; j++) {
        accD[i][j] = __builtin_amdgcn_mfma_f32_16x16x32_bf16(aF[i], bF[j], accD[i][j], 0, 0, 0);
        accN[i][j] = __builtin_amdgcn_mfma_f32_16x16x32_bf16(aF[i], cF[j], accN[i][j], 0, 0, 0);
      }
    __syncthreads();
  }

#pragma unroll
  for (int i = 0; i < 4; i++) {
    const int rowb = m0 + waveM + i * 16 + quad * 4;
#pragma unroll
    for (int j = 0; j < 4; j++) {
      const int col = n0 + waveN + j * 16 + ll;
#pragma unroll
      for (int r = 0; r < 4; r++) {
        const long idx = (long)(rowb + r) * D + col;
        const float q  = b2f(Qb[idx]);
        const float sg = 1.0f / (1.0f + __expf(-q));
        Ytb[idx] = f2b(sg * accN[i][j][r] / accD[i][j][r]);
      }
    }
  }
}

// exp_w[t,s] = exp(w[t,s] - max_s w[t,s]) ; w read per flag dtype
__global__ __launch_bounds__(256)
void expw_kernel(const void* __restrict__ w, u16* __restrict__ ew,
                 const int* __restrict__ flag)
{
  const int fl = flag[0];
  const int t = blockIdx.x;
  const int tid = threadIdx.x;
  float v[4];
  float m = -1e30f;
#pragma unroll
  for (int i = 0; i < 4; i++) {
    const long idx = (long)t * 1024 + tid + i * 256;
    float val = fl ? ((const float*)w)[idx] : b2f(((const u16*)w)[idx]);
    v[i] = val; m = fmaxf(m, val);
  }
#pragma unroll
  for (int off = 32; off > 0; off >>= 1) m = fmaxf(m, __shfl_xor(m, off, 64));
  __shared__ float sm[4];
  if ((tid & 63) == 0) sm[tid >> 6] = m;
  __syncthreads();
  m = fmaxf(fmaxf(sm[0], sm[1]), fmaxf(sm[2], sm[3]));
  u16* orow = ew + (long)t * 1024;
#pragma unroll
  for (int i = 0; i < 4; i++) orow[tid + i * 256] = f2b(__expf(v[i] - m));
}

// Kmax[t,d] = max_b K[b,t,d]
__global__ __launch_bounds__(256)
void kmax_kernel(const u16* __restrict__ K, u16* __restrict__ Km)
{
  const long TD = 1024L * 512;
  const long base = ((long)blockIdx.x * 256 + threadIdx.x) * 8;
  float m[8];
#pragma unroll
  for (int j = 0; j < 8; j++) m[j] = -1e30f;
  for (int b = 0; b < 32; b++) {
    uint4 u = *(const uint4*)(K + b * TD + base);
    const u16* p = (const u16*)&u;
#pragma unroll
    for (int j = 0; j < 8; j++) m[j] = fmaxf(m[j], b2f(p[j]));
  }
  u16 outv[8];
#pragma unroll
  for (int j = 0; j < 8; j++) outv[j] = f2b(m[j]);
  *(uint4*)(Km + base) = *(const uint4*)outv;
}

// P = exp(K - Kmax), PV = P*V ; write transposed: Pt[b,d,s], PVt[b,d,s]
__global__ __launch_bounds__(256)
void pexp_kernel(const u16* __restrict__ K, const u16* __restrict__ V,
                 const u16* __restrict__ Km,
                 u16* __restrict__ Pt, u16* __restrict__ PVt)
{
  const int T = 1024, D = 512;
  const long TD = (long)T * D;
  const int s0 = blockIdx.x * 64;
  const int d0 = blockIdx.y * 64;
  const int b  = blockIdx.z;
  __shared__ u16 lp[64 * 66];
  __shared__ u16 lpv[64 * 66];
  const int tid  = threadIdx.x;
  const int srow = tid >> 3;
  const int c8   = (tid & 7) * 8;

#pragma unroll
  for (int h = 0; h < 2; h++) {
    const int s = srow + h * 32;
    const long gidx = (long)b * TD + (long)(s0 + s) * D + d0 + c8;
    uint4 ku = *(const uint4*)(K + gidx);
    uint4 vu = *(const uint4*)(V + gidx);
    uint4 mu = *(const uint4*)(Km + (long)(s0 + s) * D + d0 + c8);
    const u16* kp = (const u16*)&ku;
    const u16* vp = (const u16*)&vu;
    const u16* mp = (const u16*)&mu;
#pragma unroll
    for (int j = 0; j < 8; j++) {
      float p  = __expf(b2f(kp[j]) - b2f(mp[j]));
      float pv = p * b2f(vp[j]);
      lp[s * 66 + c8 + j]  = f2b(p);
      lpv[s * 66 + c8 + j] = f2b(pv);
    }
  }
  __syncthreads();

  const int lane = tid & 63;
  const int wv   = tid >> 6;
#pragma unroll
  for (int it = 0; it < 16; it++) {
    const int d = wv * 16 + it;
    const long oidx = (long)b * TD + (long)(d0 + d) * T + s0 + lane;
    Pt[oidx]  = lp[lane * 66 + d];
    PVt[oidx] = lpv[lane * 66 + d];
  }
}

extern "C" void kernel_launch(void* const* d_in, const int* in_sizes, int n_in,
                              void* d_out, int out_size, void* d_ws, size_t ws_size,
                              hipStream_t stream)
{
  const int B = 32, T = 1024, D = 512;
  const long TD = (long)T * D;
  const void* x    = d_in[0];
  const void* Wk_w = d_in[1];
  const void* Wk_b = d_in[2];
  const void* Wv_w = d_in[3];
  const void* Wv_b = d_in[4];
  const void* Wq_w = d_in[5];
  const void* Wq_b = d_in[6];
  const void* w    = d_in[7];
  const void* Wo_w = d_in[8];
  const void* Wo_b = d_in[9];

  char* ws = (char*)d_ws;
  const size_t MB = 1024 * 1024;
  // fixed region: 70 MB
  u16* xb   = (u16*)(ws + 0);         // 32MB  [B*T, D] bf16
  u16* Kbuf = (u16*)(ws + 32 * MB);   // 32MB  [B, T, D]
  u16* ewb  = (u16*)(ws + 64 * MB);   // 2MB   [T, T]
  u16* kmb  = (u16*)(ws + 66 * MB);   // 1MB   [T, D]
  u16* Wkb  = (u16*)(ws + 67 * MB);
  u16* Wvb  = (u16*)(ws + 67 * MB + 512 * 1024);
  u16* Wqb  = (u16*)(ws + 68 * MB);
  u16* Wob  = (u16*)(ws + 68 * MB + 512 * 1024);
  int* flag = (int*)(ws + 69 * MB);
  char* ck  = ws + 70 * MB;           // chunk region: 4 bufs x NB*2MB

  // NB = batches per chunk: full batch if ws allows (fill counter says 256 MiB)
  const int NB = (ws_size >= (size_t)(70 + 4 * 64) * MB) ? 32 : 4;
  const int NC = B / NB;
  const size_t cb = (size_t)NB * TD * sizeof(u16);
  u16* Vc   = (u16*)(ck);
  u16* Ptc  = (u16*)(ck + cb);
  u16* PVtc = (u16*)(ck + 2 * cb);
  u16* Qc   = (u16*)(ck + 3 * cb);
  u16* Ytc  = Vc;   // Vc dead after pexp

  dim3 blk(256);

  // 0) dtype detect + normalize inputs to bf16
  detect_kernel<<<dim3(1), blk, 0, stream>>>((const u16*)x, flag);
  conv_kernel<<<dim3(8192), blk, 0, stream>>>(x,    xb,  (long)B * T * D, flag);
  conv_kernel<<<dim3(128),  blk, 0, stream>>>(Wk_w, Wkb, (long)D * D, flag);
  conv_kernel<<<dim3(128),  blk, 0, stream>>>(Wv_w, Wvb, (long)D * D, flag);
  conv_kernel<<<dim3(128),  blk, 0, stream>>>(Wq_w, Wqb, (long)D * D, flag);
  conv_kernel<<<dim3(128),  blk, 0, stream>>>(Wo_w, Wob, (long)D * D, flag);

  // 1) exp_w
  expw_kernel<<<dim3(1024), blk, 0, stream>>>(w, ewb, flag);

  // 2) K projection full batch
  dim3 gK((B * T) / 128, D / 128, 1);
  gemm_bt<0><<<gK, blk, 0, stream>>>(xb, Wkb, Wk_b, Kbuf, flag, B * T, D, D, 0);

  // 3) Kmax over batch
  kmax_kernel<<<dim3(256), blk, 0, stream>>>(Kbuf, kmb);

  // 4) per-chunk pipeline (one iteration when NB=32)
  dim3 gP((NB * T) / 128, D / 128, 1);
  dim3 gA(T / 128, D / 128, NB);
  for (int c = 0; c < NC; c++) {
    const long off = (long)c * NB * TD;

    gemm_bt<0><<<gP, blk, 0, stream>>>(xb + off, Wvb, Wv_b, Vc, flag, NB * T, D, D, 0);
    gemm_bt<0><<<gP, blk, 0, stream>>>(xb + off, Wqb, Wq_b, Qc, flag, NB * T, D, D, 0);

    pexp_kernel<<<dim3(16, 8, NB), blk, 0, stream>>>(Kbuf + off, Vc, kmb, Ptc, PVtc);

    // num/den fused: Yt = sigmoid(Q) * (ew @ PVt) / (ew @ Pt)
    gemm_aft<<<gA, blk, 0, stream>>>(ewb, Ptc, PVtc, Qc, Ytc);

    // out = Yt @ Wo^T + b
    gemm_bt<3><<<gP, blk, 0, stream>>>(Ytc, Wob, Wo_b, d_out, flag, NB * T, D, D, off);
  }
}

// Round 6
// 472.292 us; speedup vs baseline: 2.2684x; 1.9846x over previous
//
#include <hip/hip_runtime.h>
#include <stdint.h>

typedef unsigned short u16;
typedef __attribute__((ext_vector_type(4))) float f32x4;
typedef __attribute__((ext_vector_type(8))) __bf16 bf16x8;

__device__ __forceinline__ float b2f(u16 u) {
  union { unsigned int i; float f; } v; v.i = ((unsigned int)u) << 16; return v.f;
}
__device__ __forceinline__ u16 f2b(float f) {
  union { float f; unsigned int i; } v; v.f = f;
  unsigned int x = v.i;
  return (u16)((x + 0x7fffu + ((x >> 16) & 1u)) >> 16);
}

__device__ __forceinline__ void async_ld16(const u16* g, u16* l) {
  __builtin_amdgcn_global_load_lds((const __attribute__((address_space(1))) void*)g,
                                   (__attribute__((address_space(3))) void*)l, 16, 0, 0);
}

// ---- dtype detection: flag=1 if inputs are f32, 0 if bf16 ------------------
__global__ void detect_kernel(const u16* __restrict__ x, int* __restrict__ flag)
{
  const int tid = threadIdx.x;
  int found = 0;
  for (int i = tid; i < 32768; i += 256) {
    u16 u = x[i];
    if ((u & 0x7F80u) == 0x7F80u) found = 1;
  }
  unsigned long long m = __ballot(found != 0);
  __shared__ int sf[4];
  if ((tid & 63) == 0) sf[tid >> 6] = (m != 0ULL) ? 1 : 0;
  __syncthreads();
  if (tid == 0) flag[0] = (sf[0] | sf[1] | sf[2] | sf[3]);
}

__global__ __launch_bounds__(256)
void conv_kernel(const void* __restrict__ in, u16* __restrict__ out, long n,
                 const int* __restrict__ flag)
{
  const long i = ((long)blockIdx.x * 256 + threadIdx.x) * 8;
  if (i >= n) return;
  if (flag[0]) {
    const float* p = (const float*)in + i;
    u16 o[8];
#pragma unroll
    for (int j = 0; j < 8; j++) o[j] = f2b(p[j]);
    *(uint4*)(out + i) = *(const uint4*)o;
  } else {
    *(uint4*)(out + i) = *(const uint4*)((const u16*)in + i);
  }
}

#define BM 128
#define BN 128
#define BK 32

// Generic BT GEMM. EPI 0: C(bf16)=acc+bias[n]. EPI 3: flag-dtype store at strideC+idx.
template<int EPI>
__global__ __launch_bounds__(256)
void gemm_bt(const u16* __restrict__ A, const u16* __restrict__ B,
             const void* __restrict__ bias, void* __restrict__ Cv,
             const int* __restrict__ flag,
             int M, int N, int K, long strideC)
{
  __shared__ __align__(16) u16 sA[BM * BK];
  __shared__ __align__(16) u16 sB[BN * BK];

  const int tid  = threadIdx.x;
  const int lane = tid & 63;
  const int wv   = tid >> 6;
  const int fl = flag[0];
  u16* Cb16 = (u16*)Cv;

  const int m0 = blockIdx.x * BM;
  const int n0 = blockIdx.y * BN;

  const int ldRow = wv * 32;
  const int lr = lane >> 2;
  const int lc = lane & 3;
  const u16* gA = A + (long)(m0 + ldRow + lr) * K + lc * 8;
  const u16* gB = B + (long)(n0 + ldRow + lr) * K + lc * 8;
  u16* lA0 = sA + (ldRow + lr) * BK + lc * 8;
  u16* lA1 = sA + (ldRow + 16 + lr) * BK + lc * 8;
  u16* lB0 = sB + (ldRow + lr) * BK + lc * 8;
  u16* lB1 = sB + (ldRow + 16 + lr) * BK + lc * 8;

  f32x4 acc[4][4];
#pragma unroll
  for (int i = 0; i < 4; i++)
#pragma unroll
    for (int j = 0; j < 4; j++) acc[i][j] = (f32x4)0.0f;

  const int waveM = (wv >> 1) * 64;
  const int waveN = (wv & 1) * 64;
  const int quad  = lane >> 4;
  const int ll    = lane & 15;

  for (int k0 = 0; k0 < K; k0 += BK) {
    async_ld16(gA,          lA0);
    async_ld16(gA + 16 * K, lA1);
    async_ld16(gB,          lB0);
    async_ld16(gB + 16 * K, lB1);
    gA += BK; gB += BK;
    __syncthreads();

    bf16x8 aF[4], bF[4];
#pragma unroll
    for (int i = 0; i < 4; i++) {
      aF[i] = *(const bf16x8*)(sA + (waveM + i * 16 + ll) * BK + quad * 8);
      bF[i] = *(const bf16x8*)(sB + (waveN + i * 16 + ll) * BK + quad * 8);
    }
#pragma unroll
    for (int i = 0; i < 4; i++)
#pragma unroll
      for (int j = 0; j < 4; j++)
        acc[i][j] = __builtin_amdgcn_mfma_f32_16x16x32_bf16(aF[i], bF[j], acc[i][j], 0, 0, 0);
    __syncthreads();
  }

#pragma unroll
  for (int i = 0; i < 4; i++) {
    const int rowb = m0 + waveM + i * 16 + quad * 4;
#pragma unroll
    for (int j = 0; j < 4; j++) {
      const int col = n0 + waveN + j * 16 + ll;
      const float bv = fl ? ((const float*)bias)[col] : b2f(((const u16*)bias)[col]);
#pragma unroll
      for (int r = 0; r < 4; r++) {
        const long idx = (long)(rowb + r) * N + col;
        const float v = acc[i][j][r] + bv;
        if (EPI == 0) {
          Cb16[idx] = f2b(v);
        } else {
          const long g = strideC + idx;
          if (fl) ((float*)Cv)[g] = v;
          else    ((u16*)Cv)[g]   = f2b(v);
        }
      }
    }
  }
}

// Fused K/V/Q projection: A = x [M, 512], B = Wpack [1536, 512] (Wk;Wv;Wq rows),
// cols [0,512)->K, [512,1024)->V, [1024,1536)->Q, each [M, 512] bf16 + bias.
__global__ __launch_bounds__(256)
void gemm_proj3(const u16* __restrict__ A, const u16* __restrict__ Bw,
                const void* __restrict__ kb, const void* __restrict__ vb,
                const void* __restrict__ qb,
                u16* __restrict__ Kp, u16* __restrict__ Vp, u16* __restrict__ Qp,
                const int* __restrict__ flag, int M)
{
  const int KD = 512;
  __shared__ __align__(16) u16 sA[BM * BK];
  __shared__ __align__(16) u16 sB[BN * BK];

  const int tid  = threadIdx.x;
  const int lane = tid & 63;
  const int wv   = tid >> 6;
  const int fl = flag[0];

  const int m0 = blockIdx.x * BM;
  const int n0 = blockIdx.y * BN;

  const int ldRow = wv * 32;
  const int lr = lane >> 2;
  const int lc = lane & 3;
  const u16* gA = A  + (long)(m0 + ldRow + lr) * KD + lc * 8;
  const u16* gB = Bw + (long)(n0 + ldRow + lr) * KD + lc * 8;
  u16* lA0 = sA + (ldRow + lr) * BK + lc * 8;
  u16* lA1 = sA + (ldRow + 16 + lr) * BK + lc * 8;
  u16* lB0 = sB + (ldRow + lr) * BK + lc * 8;
  u16* lB1 = sB + (ldRow + 16 + lr) * BK + lc * 8;

  f32x4 acc[4][4];
#pragma unroll
  for (int i = 0; i < 4; i++)
#pragma unroll
    for (int j = 0; j < 4; j++) acc[i][j] = (f32x4)0.0f;

  const int waveM = (wv >> 1) * 64;
  const int waveN = (wv & 1) * 64;
  const int quad  = lane >> 4;
  const int ll    = lane & 15;

  for (int k0 = 0; k0 < KD; k0 += BK) {
    async_ld16(gA,           lA0);
    async_ld16(gA + 16 * KD, lA1);
    async_ld16(gB,           lB0);
    async_ld16(gB + 16 * KD, lB1);
    gA += BK; gB += BK;
    __syncthreads();

    bf16x8 aF[4], bF[4];
#pragma unroll
    for (int i = 0; i < 4; i++) {
      aF[i] = *(const bf16x8*)(sA + (waveM + i * 16 + ll) * BK + quad * 8);
      bF[i] = *(const bf16x8*)(sB + (waveN + i * 16 + ll) * BK + quad * 8);
    }
#pragma unroll
    for (int i = 0; i < 4; i++)
#pragma unroll
      for (int j = 0; j < 4; j++)
        acc[i][j] = __builtin_amdgcn_mfma_f32_16x16x32_bf16(aF[i], bF[j], acc[i][j], 0, 0, 0);
    __syncthreads();
  }

#pragma unroll
  for (int i = 0; i < 4; i++) {
    const int rowb = m0 + waveM + i * 16 + quad * 4;
#pragma unroll
    for (int j = 0; j < 4; j++) {
      const int col = n0 + waveN + j * 16 + ll;   // [0,1536)
      const int sel = col >> 9;
      const int cs  = col & 511;
      const void* bp = (sel == 0) ? kb : (sel == 1) ? vb : qb;
      u16* dst = (sel == 0) ? Kp : (sel == 1) ? Vp : Qp;
      const float bv = fl ? ((const float*)bp)[cs] : b2f(((const u16*)bp)[cs]);
#pragma unroll
      for (int r = 0; r < 4; r++)
        dst[(long)(rowb + r) * 512 + cs] = f2b(acc[i][j][r] + bv);
    }
  }
}

// Dual GEMM: num = ew @ PVt^T, den = ew @ Pt^T ; Yt = sigmoid(Q)*num/den.
__global__ __launch_bounds__(256)
void gemm_aft(const u16* __restrict__ ew, const u16* __restrict__ Pt,
              const u16* __restrict__ PVt, const u16* __restrict__ Q,
              u16* __restrict__ Yt)
{
  const int T = 1024, D = 512;
  __shared__ __align__(16) u16 sA[BM * BK];
  __shared__ __align__(16) u16 sB[BN * BK];
  __shared__ __align__(16) u16 sC[BN * BK];

  const int tid  = threadIdx.x;
  const int lane = tid & 63;
  const int wv   = tid >> 6;
  const int b    = blockIdx.z;

  const u16* Ptb  = Pt  + (long)b * D * T;
  const u16* PVtb = PVt + (long)b * D * T;
  const u16* Qb   = Q   + (long)b * T * D;
  u16*       Ytb  = Yt  + (long)b * T * D;

  const int m0 = blockIdx.x * BM;
  const int n0 = blockIdx.y * BN;

  const int ldRow = wv * 32;
  const int lr = lane >> 2;
  const int lc = lane & 3;
  const u16* gA = ew   + (long)(m0 + ldRow + lr) * T + lc * 8;
  const u16* gB = Ptb  + (long)(n0 + ldRow + lr) * T + lc * 8;
  const u16* gC = PVtb + (long)(n0 + ldRow + lr) * T + lc * 8;
  u16* lA0 = sA + (ldRow + lr) * BK + lc * 8;
  u16* lA1 = sA + (ldRow + 16 + lr) * BK + lc * 8;
  u16* lB0 = sB + (ldRow + lr) * BK + lc * 8;
  u16* lB1 = sB + (ldRow + 16 + lr) * BK + lc * 8;
  u16* lC0 = sC + (ldRow + lr) * BK + lc * 8;
  u16* lC1 = sC + (ldRow + 16 + lr) * BK + lc * 8;

  f32x4 accN[4][4], accD[4][4];
#pragma unroll
  for (int i = 0; i < 4; i++)
#pragma unroll
    for (int j = 0; j < 4; j++) { accN[i][j] = (f32x4)0.0f; accD[i][j] = (f32x4)0.0f; }

  const int waveM = (wv >> 1) * 64;
  const int waveN = (wv & 1) * 64;
  const int quad  = lane >> 4;
  const int ll    = lane & 15;

  for (int k0 = 0; k0 < T; k0 += BK) {
    async_ld16(gA,          lA0);
    async_ld16(gA + 16 * T, lA1);
    async_ld16(gB,          lB0);
    async_ld16(gB + 16 * T, lB1);
    async_ld16(gC,          lC0);
    async_ld16(gC + 16 * T, lC1);
    gA += BK; gB += BK; gC += BK;
    __syncthreads();

    bf16x8 aF[4], bF[4], cF[4];
#pragma unroll
    for (int i = 0; i < 4; i++) {
      aF[i] = *(const bf16x8*)(sA + (waveM + i * 16 + ll) * BK + quad * 8);
      bF[i] = *(const bf16x8*)(sB + (waveN + i * 16 + ll) * BK + quad * 8);
      cF[i] = *(const bf16x8*)(sC + (waveN + i * 16 + ll) * BK + quad * 8);
    }
#pragma unroll
    for (int i = 0; i < 4; i++)
#pragma unroll
      for (int j = 0; j < 4; j++) {
        accD[i][j] = __builtin_amdgcn_mfma_f32_16x16x32_bf16(aF[i], bF[j], accD[i][j], 0, 0, 0);
        accN[i][j] = __builtin_amdgcn_mfma_f32_16x16x32_bf16(aF[i], cF[j], accN[i][j], 0, 0, 0);
      }
    __syncthreads();
  }

#pragma unroll
  for (int i = 0; i < 4; i++) {
    const int rowb = m0 + waveM + i * 16 + quad * 4;
#pragma unroll
    for (int j = 0; j < 4; j++) {
      const int col = n0 + waveN + j * 16 + ll;
#pragma unroll
      for (int r = 0; r < 4; r++) {
        const long idx = (long)(rowb + r) * D + col;
        const float q  = b2f(Qb[idx]);
        const float sg = 1.0f / (1.0f + __expf(-q));
        Ytb[idx] = f2b(sg * accN[i][j][r] / accD[i][j][r]);
      }
    }
  }
}

__global__ __launch_bounds__(256)
void expw_kernel(const void* __restrict__ w, u16* __restrict__ ew,
                 const int* __restrict__ flag)
{
  const int fl = flag[0];
  const int t = blockIdx.x;
  const int tid = threadIdx.x;
  float v[4];
  float m = -1e30f;
#pragma unroll
  for (int i = 0; i < 4; i++) {
    const long idx = (long)t * 1024 + tid + i * 256;
    float val = fl ? ((const float*)w)[idx] : b2f(((const u16*)w)[idx]);
    v[i] = val; m = fmaxf(m, val);
  }
#pragma unroll
  for (int off = 32; off > 0; off >>= 1) m = fmaxf(m, __shfl_xor(m, off, 64));
  __shared__ float sm[4];
  if ((tid & 63) == 0) sm[tid >> 6] = m;
  __syncthreads();
  m = fmaxf(fmaxf(sm[0], sm[1]), fmaxf(sm[2], sm[3]));
  u16* orow = ew + (long)t * 1024;
#pragma unroll
  for (int i = 0; i < 4; i++) orow[tid + i * 256] = f2b(__expf(v[i] - m));
}

__global__ __launch_bounds__(256)
void kmax_kernel(const u16* __restrict__ K, u16* __restrict__ Km)
{
  const long TD = 1024L * 512;
  const long base = ((long)blockIdx.x * 256 + threadIdx.x) * 8;
  float m[8];
#pragma unroll
  for (int j = 0; j < 8; j++) m[j] = -1e30f;
  for (int b = 0; b < 32; b++) {
    uint4 u = *(const uint4*)(K + b * TD + base);
    const u16* p = (const u16*)&u;
#pragma unroll
    for (int j = 0; j < 8; j++) m[j] = fmaxf(m[j], b2f(p[j]));
  }
  u16 outv[8];
#pragma unroll
  for (int j = 0; j < 8; j++) outv[j] = f2b(m[j]);
  *(uint4*)(Km + base) = *(const uint4*)outv;
}

__global__ __launch_bounds__(256)
void pexp_kernel(const u16* __restrict__ K, const u16* __restrict__ V,
                 const u16* __restrict__ Km,
                 u16* __restrict__ Pt, u16* __restrict__ PVt)
{
  const int T = 1024, D = 512;
  const long TD = (long)T * D;
  const int s0 = blockIdx.x * 64;
  const int d0 = blockIdx.y * 64;
  const int b  = blockIdx.z;
  __shared__ u16 lp[64 * 66];
  __shared__ u16 lpv[64 * 66];
  const int tid  = threadIdx.x;
  const int srow = tid >> 3;
  const int c8   = (tid & 7) * 8;

#pragma unroll
  for (int h = 0; h < 2; h++) {
    const int s = srow + h * 32;
    const long gidx = (long)b * TD + (long)(s0 + s) * D + d0 + c8;
    uint4 ku = *(const uint4*)(K + gidx);
    uint4 vu = *(const uint4*)(V + gidx);
    uint4 mu = *(const uint4*)(Km + (long)(s0 + s) * D + d0 + c8);
    const u16* kp = (const u16*)&ku;
    const u16* vp = (const u16*)&vu;
    const u16* mp = (const u16*)&mu;
#pragma unroll
    for (int j = 0; j < 8; j++) {
      float p  = __expf(b2f(kp[j]) - b2f(mp[j]));
      float pv = p * b2f(vp[j]);
      lp[s * 66 + c8 + j]  = f2b(p);
      lpv[s * 66 + c8 + j] = f2b(pv);
    }
  }
  __syncthreads();

  const int lane = tid & 63;
  const int wv   = tid >> 6;
#pragma unroll
  for (int it = 0; it < 16; it++) {
    const int d = wv * 16 + it;
    const long oidx = (long)b * TD + (long)(d0 + d) * T + s0 + lane;
    Pt[oidx]  = lp[lane * 66 + d];
    PVt[oidx] = lpv[lane * 66 + d];
  }
}

extern "C" void kernel_launch(void* const* d_in, const int* in_sizes, int n_in,
                              void* d_out, int out_size, void* d_ws, size_t ws_size,
                              hipStream_t stream)
{
  const int B = 32, T = 1024, D = 512;
  const long TD = (long)T * D;
  const void* x    = d_in[0];
  const void* Wk_w = d_in[1];
  const void* Wk_b = d_in[2];
  const void* Wv_w = d_in[3];
  const void* Wv_b = d_in[4];
  const void* Wq_w = d_in[5];
  const void* Wq_b = d_in[6];
  const void* w    = d_in[7];
  const void* Wo_w = d_in[8];
  const void* Wo_b = d_in[9];

  char* ws = (char*)d_ws;
  const size_t MB = 1024 * 1024;
  u16* xb    = (u16*)(ws + 0);          // 32MB [B*T, D]
  u16* Kbuf  = (u16*)(ws + 32 * MB);    // 32MB (aliased as Yt after pexp)
  u16* ewb   = (u16*)(ws + 64 * MB);    // 2MB
  u16* kmb   = (u16*)(ws + 66 * MB);    // 1MB
  u16* Wpack = (u16*)(ws + 67 * MB);    // 1.5MB: Wk;Wv;Wq rows [1536, 512]
  u16* Wvb   = Wpack + 512 * 512;
  u16* Wqb   = Wpack + 2 * 512 * 512;
  u16* Wob   = (u16*)(ws + 68 * MB + 512 * 1024); // 0.5MB
  int* flag  = (int*)(ws + 69 * MB);
  u16* Ytb   = Kbuf;

  dim3 blk(256);

  detect_kernel<<<dim3(1), blk, 0, stream>>>((const u16*)x, flag);
  conv_kernel<<<dim3(8192), blk, 0, stream>>>(x,    xb,    (long)B * T * D, flag);
  conv_kernel<<<dim3(128),  blk, 0, stream>>>(Wk_w, Wpack, (long)D * D, flag);
  conv_kernel<<<dim3(128),  blk, 0, stream>>>(Wv_w, Wvb,   (long)D * D, flag);
  conv_kernel<<<dim3(128),  blk, 0, stream>>>(Wq_w, Wqb,   (long)D * D, flag);
  conv_kernel<<<dim3(128),  blk, 0, stream>>>(Wo_w, Wob,   (long)D * D, flag);
  expw_kernel<<<dim3(1024), blk, 0, stream>>>(w, ewb, flag);

  if (ws_size >= 200 * MB) {
    // ---- full-batch single-pass path ----
    u16* Vb   = (u16*)(ws + 70 * MB);   // 32MB
    u16* Qb   = (u16*)(ws + 102 * MB);  // 32MB
    u16* Ptb  = (u16*)(ws + 134 * MB);  // 32MB
    u16* PVtb = (u16*)(ws + 166 * MB);  // 32MB -> ends 198MB

    // K,V,Q in one GEMM: N = 1536
    gemm_proj3<<<dim3((B * T) / 128, 12), blk, 0, stream>>>(
        xb, Wpack, Wk_b, Wv_b, Wq_b, Kbuf, Vb, Qb, flag, B * T);

    kmax_kernel<<<dim3(256), blk, 0, stream>>>(Kbuf, kmb);
    pexp_kernel<<<dim3(16, 8, 32), blk, 0, stream>>>(Kbuf, Vb, kmb, Ptb, PVtb);

    // Yt aliases Kbuf (dead after pexp)
    gemm_aft<<<dim3(T / 128, D / 128, 32), blk, 0, stream>>>(ewb, Ptb, PVtb, Qb, Ytb);

    gemm_bt<3><<<dim3((B * T) / 128, D / 128), blk, 0, stream>>>(
        Ytb, Wob, Wo_b, d_out, flag, B * T, D, D, 0);
  } else {
    // ---- chunked fallback (NB=4), R5 structure ----
    const int NB = 4, NC = B / NB;
    char* ck = ws + 70 * MB;
    const size_t cb = (size_t)NB * TD * sizeof(u16);
    u16* Vc   = (u16*)(ck);
    u16* Ptc  = (u16*)(ck + cb);
    u16* PVtc = (u16*)(ck + 2 * cb);
    u16* Qc   = (u16*)(ck + 3 * cb);
    u16* Ytc  = Vc;

    gemm_bt<0><<<dim3((B * T) / 128, D / 128), blk, 0, stream>>>(
        xb, Wpack, Wk_b, Kbuf, flag, B * T, D, D, 0);
    kmax_kernel<<<dim3(256), blk, 0, stream>>>(Kbuf, kmb);

    dim3 gP((NB * T) / 128, D / 128, 1);
    dim3 gA(T / 128, D / 128, NB);
    for (int c = 0; c < NC; c++) {
      const long off = (long)c * NB * TD;
      gemm_bt<0><<<gP, blk, 0, stream>>>(xb + off, Wvb, Wv_b, Vc, flag, NB * T, D, D, 0);
      gemm_bt<0><<<gP, blk, 0, stream>>>(xb + off, Wqb, Wq_b, Qc, flag, NB * T, D, D, 0);
      pexp_kernel<<<dim3(16, 8, NB), blk, 0, stream>>>(Kbuf + off, Vc, kmb, Ptc, PVtc);
      gemm_aft<<<gA, blk, 0, stream>>>(ewb, Ptc, PVtc, Qc, Ytc);
      gemm_bt<3><<<gP, blk, 0, stream>>>(Ytc, Wob, Wo_b, d_out, flag, NB * T, D, D, off);
    }
  }
}